// Round 13
// baseline (178.996 us; speedup 1.0000x reference)
//
#include <hip/hip_runtime.h>
#include <hip/hip_bf16.h>

// MultiHeadAttention fused pipeline. FP32 in/out, bf16 MFMA compute, fp32 accum.
// B=2 T=2048 C=1024 H=16 D=64.
// EVERY MFMA operand in EVERY kernel now loads as a coalesced fragment-major
// 1KB wave-burst; NO kernel except attention's per-wave P round-trip uses LDS,
// and NO kernel has a __syncthreads in its main loop.
// Stage 0: convert x,W* -> bf16 fragment-major.
// Stage 1: QKV GEMM, zero-LDS streaming (round-11 proven); RoPE + exp2 scale
//          fused; writes Q [B,H,T,D], K in QK-B-frag-major, V in PV-B-frag-major.
// Stage 2: attention, ZERO BARRIERS: K/V fragments streamed global->VGPR,
//          p=exp2(s) no-max softmax, l via ones-MFMA, per-wave P LDS only.
//          O written fragment-major for the streaming out-GEMM.
// Stage 3: out GEMM, zero-LDS streaming (round-12 proven) -> fp32 d_out.
//
// MFMA layouts (HW-verified): A[m=lane&15][k=quad*8+j]; B[n=lane&15][k=quad*8+j];
// C/D: row=quad*4+reg, col=lane&15.
// K frag map: (t,d) -> frag(c=t>>6, nt=(t>>4)&3, ks=d>>5),
//             elem ((d&31)>>3)*128 + (t&15)*8 + (d&7).
// V frag map: (t,d) -> frag(c=t>>6, dt=d>>4, ks=(t>>5)&1),
//             elem ((t&31)>>3)*128 + (d&15)*8 + (t&7).

typedef __hip_bfloat16 bf16;
typedef __attribute__((ext_vector_type(8))) short bf16x8;
typedef __attribute__((ext_vector_type(4))) float f32x4;
typedef __attribute__((ext_vector_type(4))) short short4v;

#define MFMA16(a, b, c) __builtin_amdgcn_mfma_f32_16x16x32_bf16((a), (b), (c), 0, 0, 0)

constexpr int Bn = 2, Hn = 16, Tn = 2048, Dn = 64, Cn = 1024;
constexpr size_t NE = (size_t)Bn * Tn * Cn;   // 4,194,304
constexpr size_t WE = (size_t)Cn * Cn;        // 1,048,576
constexpr float QSCALE = 0.125f * 1.44269504088896f;   // 1/8 * log2(e)

__device__ inline unsigned short bfbits(float x) {
    bf16 b = __float2bfloat16(x);
    return *(unsigned short*)&b;
}

__device__ inline bf16x8 pack8(f32x4 a, f32x4 b) {
    bf16x8 r;
#pragma unroll
    for (int i = 0; i < 4; ++i) r[i] = (short)bfbits(a[i]);
#pragma unroll
    for (int i = 0; i < 4; ++i) r[4 + i] = (short)bfbits(b[i]);
    return r;
}

// ---------------------------------------------------------------- convert
// blocks [0,2048): x -> fragment-major (256 m-tiles x 32 k-chunks).
// blocks [2048,4096): W* -> fragment-major (64 n-tiles x 32 k-chunks each).
__global__ __launch_bounds__(256) void convert_kernel(
    const float* __restrict__ x, const float* __restrict__ wq,
    const float* __restrict__ wk, const float* __restrict__ wv,
    const float* __restrict__ wo, bf16* __restrict__ dst)
{
    int blk = blockIdx.x;
    int lane = threadIdx.x & 63;
    int lx = lane & 15, quad = lane >> 4;
    const float* src;
    size_t doff;
    if (blk < 2048) {
        int frag = blk * 4 + (threadIdx.x >> 6);   // 0..8191
        int mt = frag >> 5, kc = frag & 31;
        src = x + (size_t)(mt * 16 + lx) * Cn + kc * 32 + quad * 8;
        doff = (size_t)frag * 512 + lane * 8;
    } else {
        int w = (blk - 2048) >> 9, b = (blk - 2048) & 511;
        const float* s4[4] = {wq, wk, wv, wo};
        int frag = b * 4 + (threadIdx.x >> 6);     // 0..2047
        int nb = frag >> 5, kc = frag & 31;
        src = s4[w] + (size_t)(nb * 16 + lx) * Cn + kc * 32 + quad * 8;
        doff = NE + (size_t)w * WE + (size_t)frag * 512 + lane * 8;
    }
    f32x4 a = *(const f32x4*)(src);
    f32x4 b2 = *(const f32x4*)(src + 4);
    *(bf16x8*)(dst + doff) = pack8(a, b2);
}

// ---------------------------------------------------------------- QKV GEMM
// ZERO-LDS streaming GEMM: 4 waves (2x2), wave 64x64, K-step 32, cur/next
// prefetch, no barriers. Epilogue: Q row-major (QSCALE+RoPE), K/V frag-major.
__global__ __launch_bounds__(256) void gemm_qkv_kernel(
    const bf16* __restrict__ Xf, const bf16* __restrict__ Wbase,
    bf16* __restrict__ Qo, bf16* __restrict__ Ko, bf16* __restrict__ Vo)
{
    const int bm = blockIdx.x, bn = blockIdx.y, wsel = blockIdx.z;
    const bf16* W = Wbase + (size_t)wsel * WE;
    const int tid  = threadIdx.x;
    const int wave = tid >> 6, lane = tid & 63;
    const int lx   = lane & 15, quad = lane >> 4;
    const int wm = wave >> 1, wn = wave & 1;

    const int mt0 = bm * 8 + wm * 4;
    const int nb0 = bn * 8 + wn * 4;
    const bf16* afrag = Xf + (size_t)mt0 * 32 * 512 + (size_t)lane * 8;
    const bf16* wfrag = W + (size_t)nb0 * 32 * 512 + (size_t)lane * 8;

    f32x4 acc[4][4] = {};   // [mt][nt]
    bf16x8 acur[4], bcur[4], anxt[4], bnxt[4];
#pragma unroll
    for (int i = 0; i < 4; ++i) {
        acur[i] = *(const bf16x8*)(afrag + (size_t)i * 32 * 512);
        bcur[i] = *(const bf16x8*)(wfrag + (size_t)i * 32 * 512);
    }
    for (int kc = 0; kc < 32; ++kc) {
        if (kc < 31) {
#pragma unroll
            for (int i = 0; i < 4; ++i) {
                anxt[i] = *(const bf16x8*)(afrag + ((size_t)i * 32 + kc + 1) * 512);
                bnxt[i] = *(const bf16x8*)(wfrag + ((size_t)i * 32 + kc + 1) * 512);
            }
        }
#pragma unroll
        for (int mt = 0; mt < 4; ++mt)
#pragma unroll
            for (int nt = 0; nt < 4; ++nt)
                acc[mt][nt] = MFMA16(acur[mt], bcur[nt], acc[mt][nt]);
#pragma unroll
        for (int i = 0; i < 4; ++i) { acur[i] = anxt[i]; bcur[i] = bnxt[i]; }
    }

    const int h = bn * 2 + wn;   // 64-col wave block == one head
    if (wsel <= 1) {             // fused RoPE: pair (d, d+32) = (nt, nt+2)
#pragma unroll
        for (int mt = 0; mt < 4; ++mt)
#pragma unroll
            for (int r = 0; r < 4; ++r) {
                int mg = bm * 128 + wm * 64 + mt * 16 + quad * 4 + r;
                int t  = mg & (Tn - 1);
#pragma unroll
                for (int nt = 0; nt < 2; ++nt) {
                    int d = nt * 16 + lx;   // 0..31
                    float ang = (float)t * __expf(-(float)d * 0.2878231366f);
                    float c, s;
                    __sincosf(ang, &s, &c);
                    float a0 = acc[mt][nt][r], a1 = acc[mt][nt + 2][r];
                    acc[mt][nt][r]     = a0 * c - a1 * s;
                    acc[mt][nt + 2][r] = a1 * c + a0 * s;
                }
            }
    }

#pragma unroll
    for (int mt = 0; mt < 4; ++mt) {
        int mg0 = bm * 128 + wm * 64 + mt * 16 + quad * 4;
        int b = mg0 >> 11, tlo = mg0 & (Tn - 1);
        if (wsel == 0) {        // Q: row-major [B,H,T,D], exp2-folded scale
#pragma unroll
            for (int nt = 0; nt < 4; ++nt)
#pragma unroll
                for (int r = 0; r < 4; ++r) {
                    int d = nt * 16 + lx;
                    Qo[((size_t)(b * Hn + h) * Tn + tlo + r) * Dn + d] =
                        __float2bfloat16(acc[mt][nt][r] * QSCALE);
                }
        } else if (wsel == 1) { // K: QK-B-fragment-major per head
            bf16* Kf = Ko + (size_t)(b * Hn + h) * Tn * Dn;
            int c = tlo >> 6, ntk = (tlo >> 4) & 3;
#pragma unroll
            for (int nt = 0; nt < 4; ++nt) {
                size_t base = ((size_t)(c * 4 + ntk) * 2 + (nt >> 1)) * 512
                            + (size_t)((nt & 1) * 2 + (lx >> 3)) * 128
                            + (size_t)(tlo & 15) * 8 + (lx & 7);
#pragma unroll
                for (int r = 0; r < 4; ++r)
                    Kf[base + (size_t)r * 8] = __float2bfloat16(acc[mt][nt][r]);
            }
        } else {                // V: PV-B-fragment-major per head, 8B stores
            bf16* Vf = Vo + (size_t)(b * Hn + h) * Tn * Dn;
            int c = tlo >> 6, ksv = (tlo >> 5) & 1;
            int qv = (tlo >> 3) & 3, pos0 = tlo & 7;
#pragma unroll
            for (int nt = 0; nt < 4; ++nt) {
                short4v pk;
#pragma unroll
                for (int r = 0; r < 4; ++r) pk[r] = (short)bfbits(acc[mt][nt][r]);
                *(short4v*)&Vf[((size_t)(c * 8 + nt * 2 + ksv)) * 512
                               + (size_t)qv * 128 + (size_t)lx * 8 + pos0] = pk;
            }
        }
    }
}

// ---------------------------------------------------------------- out GEMM
// ZERO-LDS streaming (round-12 proven): block 128x64, wave 64x32, no barriers.
__global__ __launch_bounds__(256) void gemm_out_kernel(
    const bf16* __restrict__ Af, const bf16* __restrict__ W, float* __restrict__ Out)
{
    const int bm = blockIdx.x, bn = blockIdx.y;
    const int tid  = threadIdx.x;
    const int wave = tid >> 6, lane = tid & 63;
    const int lx   = lane & 15, quad = lane >> 4;
    const int wm = wave >> 1, wn = wave & 1;

    const int mt0 = bm * 8 + wm * 4;
    const int nb0 = bn * 4 + wn * 2;
    const bf16* afrag = Af + (size_t)mt0 * 32 * 512 + (size_t)lane * 8;
    const bf16* wfrag = W + (size_t)nb0 * 32 * 512 + (size_t)lane * 8;

    f32x4 acc[4][2] = {};
    bf16x8 acur[4], bcur[2], anxt[4], bnxt[2];
#pragma unroll
    for (int i = 0; i < 4; ++i)
        acur[i] = *(const bf16x8*)(afrag + (size_t)i * 32 * 512);
#pragma unroll
    for (int i = 0; i < 2; ++i)
        bcur[i] = *(const bf16x8*)(wfrag + (size_t)i * 32 * 512);
    for (int kc = 0; kc < 32; ++kc) {
        if (kc < 31) {
#pragma unroll
            for (int i = 0; i < 4; ++i)
                anxt[i] = *(const bf16x8*)(afrag + ((size_t)i * 32 + kc + 1) * 512);
#pragma unroll
            for (int i = 0; i < 2; ++i)
                bnxt[i] = *(const bf16x8*)(wfrag + ((size_t)i * 32 + kc + 1) * 512);
        }
#pragma unroll
        for (int mt = 0; mt < 4; ++mt)
#pragma unroll
            for (int nt = 0; nt < 2; ++nt)
                acc[mt][nt] = MFMA16(acur[mt], bcur[nt], acc[mt][nt]);
#pragma unroll
        for (int i = 0; i < 4; ++i) acur[i] = anxt[i];
#pragma unroll
        for (int i = 0; i < 2; ++i) bcur[i] = bnxt[i];
    }
#pragma unroll
    for (int mt = 0; mt < 4; ++mt)
#pragma unroll
        for (int nt = 0; nt < 2; ++nt)
#pragma unroll
            for (int r = 0; r < 4; ++r) {
                int mg = bm * 128 + wm * 64 + mt * 16 + quad * 4 + r;
                int ng = bn * 64 + wn * 32 + nt * 16 + lx;
                Out[(size_t)mg * Cn + ng] = acc[mt][nt][r];
            }
}

// ---------------------------------------------------------------- Attention
// ZERO BARRIERS. 1024 blocks: f -> bh = (f&7)*4 + ((f>>3)&3), qb = 31-(f>>5).
// One 64-row q-tile per block, 4 waves x 16 rows. K/V fragments streamed
// global->VGPR (coalesced 1KB bursts from frag-major layouts). p = exp2(s),
// l via ones-MFMA, per-wave P LDS round trip (lgkmcnt only).
// O written fragment-major for the streaming out-GEMM.
__global__ __launch_bounds__(256) void attn_kernel(
    const bf16* __restrict__ Q, const bf16* __restrict__ K,
    const bf16* __restrict__ Vt, bf16* __restrict__ O)
{
    __shared__ unsigned short Pl[4][16 * 72];
    const int f  = blockIdx.x;
    const int bh = (f & 7) * 4 + ((f >> 3) & 3);
    const int qb = 31 - (f >> 5);
    const int tid  = threadIdx.x;
    const int wave = tid >> 6, lane = tid & 63;
    const int lx   = lane & 15, quad = lane >> 4;

    const bf16* Qh = Q  + (size_t)bh * Tn * Dn;
    const bf16* Kh = K  + (size_t)bh * Tn * Dn;   // frag-major: 8 frags/chunk
    const bf16* Vh = Vt + (size_t)bh * Tn * Dn;   // frag-major: 8 frags/chunk
    unsigned short* pw = &Pl[wave][0];

    const int qrowA = qb * 64 + wave * 16 + lx;   // A-frag m index
    bf16x8 aq0 = *(const bf16x8*)(Qh + (size_t)qrowA * Dn + quad * 8);
    bf16x8 aq1 = *(const bf16x8*)(Qh + (size_t)qrowA * Dn + 32 + quad * 8);

    bf16x8 ones;
#pragma unroll
    for (int i = 0; i < 8; ++i) ones[i] = (short)0x3F80;

    f32x4 acc_o[4] = {};
    f32x4 acc_l = {};
    const int row_local = wave * 16 + quad * 4;

    for (int c = 0; c <= qb; ++c) {
        const bf16* kc = Kh + (size_t)c * 4096 + (size_t)lane * 8;
        const bf16* vc = Vh + (size_t)c * 4096 + (size_t)lane * 8;
        // ---- S = Q K^T : K frags streamed (frag = nt*2 + ks)
        f32x4 accs[4] = {};
#pragma unroll
        for (int nt = 0; nt < 4; ++nt) {
            bf16x8 k0 = *(const bf16x8*)(kc + (size_t)(nt * 2) * 512);
            bf16x8 k1 = *(const bf16x8*)(kc + (size_t)(nt * 2 + 1) * 512);
            accs[nt] = MFMA16(aq0, k0, accs[nt]);
            accs[nt] = MFMA16(aq1, k1, accs[nt]);
        }
        // ---- issue V frag loads early (independent of P)
        bf16x8 vf0[4], vf1[4];
#pragma unroll
        for (int dt = 0; dt < 4; ++dt) {
            vf0[dt] = *(const bf16x8*)(vc + (size_t)(dt * 2) * 512);
            vf1[dt] = *(const bf16x8*)(vc + (size_t)(dt * 2 + 1) * 512);
        }
        // ---- p = exp2(s) -> per-wave P buffer
        if (c < qb) {
#pragma unroll
            for (int nt = 0; nt < 4; ++nt)
#pragma unroll
                for (int r = 0; r < 4; ++r)
                    pw[(quad * 4 + r) * 72 + nt * 16 + lx] = bfbits(exp2f(accs[nt][r]));
        } else {   // diagonal chunk: causal mask
#pragma unroll
            for (int nt = 0; nt < 4; ++nt) {
                int keyl = nt * 16 + lx;
#pragma unroll
                for (int r = 0; r < 4; ++r) {
                    float p = (keyl > row_local + r) ? 0.0f : exp2f(accs[nt][r]);
                    pw[(quad * 4 + r) * 72 + nt * 16 + lx] = bfbits(p);
                }
            }
        }
        asm volatile("s_waitcnt lgkmcnt(0)" ::: "memory");
        bf16x8 ap0 = *(const bf16x8*)&pw[lx * 72 + quad * 8];
        bf16x8 ap1 = *(const bf16x8*)&pw[lx * 72 + 32 + quad * 8];
        // ---- l += P . 1
        acc_l = MFMA16(ap0, ones, acc_l);
        acc_l = MFMA16(ap1, ones, acc_l);
        // ---- O += P V (V frags already in flight)
#pragma unroll
        for (int dt = 0; dt < 4; ++dt) {
            acc_o[dt] = MFMA16(ap0, vf0[dt], acc_o[dt]);
            acc_o[dt] = MFMA16(ap1, vf1[dt], acc_o[dt]);
        }
    }

    // epilogue: fragment-major O write (for streaming out-GEMM)
    const int b = bh >> 4, h = bh & 15;
    const int mtile = b * 128 + qb * 4 + wave;
#pragma unroll
    for (int dt = 0; dt < 4; ++dt) {
        int ch = h * 64 + dt * 16 + lx;            // channel
        size_t base = ((size_t)mtile * 32 + (ch >> 5)) * 512
                    + (size_t)(((ch >> 3) & 3) * 16) * 8 + (ch & 7);
#pragma unroll
        for (int r = 0; r < 4; ++r) {
            float o = acc_o[dt][r] / acc_l[r];
            O[base + (size_t)(quad * 4 + r) * 8] = __float2bfloat16(o);
        }
    }
}

// ---------------------------------------------------------------- launch
extern "C" void kernel_launch(void* const* d_in, const int* in_sizes, int n_in,
                              void* d_out, int out_size, void* d_ws, size_t ws_size,
                              hipStream_t stream)
{
    const float* x  = (const float*)d_in[0];
    const float* Wq = (const float*)d_in[1];
    const float* Wk = (const float*)d_in[2];
    const float* Wv = (const float*)d_in[3];
    const float* Wo = (const float*)d_in[4];
    float* out = (float*)d_out;

    bf16* ws = (bf16*)d_ws;
    bf16* Xf = ws;                    // x fragment-major (aliased by Ab after QKV)
    bf16* Wb = ws + NE;               // Wq,Wk,Wv,Wo bf16 SHUFFLED, contiguous
    bf16* Qb = ws + NE + 4 * WE;      // [B,H,T,D] (pre-scaled by QSCALE)
    bf16* Kb = Qb + NE;               // QK-B-fragment-major per head
    bf16* Vb = Kb + NE;               // PV-B-fragment-major per head
    bf16* Ab = Xf;                    // attention out FRAGMENT-MAJOR, reuses Xf

    convert_kernel<<<4096, 256, 0, stream>>>(x, Wq, Wk, Wv, Wo, ws);
    gemm_qkv_kernel<<<dim3(32, 8, 3), 256, 0, stream>>>(Xf, Wb, Qb, Kb, Vb);
    attn_kernel<<<1024, 256, 0, stream>>>(Qb, Kb, Vb, Ab);
    gemm_out_kernel<<<dim3(32, 16), 256, 0, stream>>>(Ab, Wb + 3 * WE, out);
}

// Round 15
// 176.781 us; speedup vs baseline: 1.0125x; 1.0125x over previous
//
#include <hip/hip_runtime.h>
#include <hip/hip_bf16.h>

// MultiHeadAttention fused pipeline. FP32 in/out, bf16 MFMA compute, fp32 accum.
// B=2 T=2048 C=1024 H=16 D=64.
// Stage 0: convert x,W* -> bf16 fragment-major (wave frag load = 1KB burst).
// Stage 1: QKV GEMM zero-LDS streaming (round-11 proven); RoPE + exp2 scale
//          fused. Q row-major; K QK-B-frag-major; V PV-B-frag-major with the
//          SIGMA key-permute (slot = 4*(key&15) + (key>>4)) matching attn's
//          packed P writes.
// Stage 2: attention: K/V frag-major chunks flat-staged in LDS ONCE per block
//          (global_load_lds: PER-LANE global addr + wave-uniform LDS base —
//          round-14 bug was a missing lane term); immediate-offset
//          ds_read_b128 frags (no swizzle VALU); p = exp2(s) no-max softmax;
//          P written as 4x ds_write_b64 (sigma-packed); l via ones-MFMA.
//          O written fragment-major.
// Stage 3: out GEMM zero-LDS streaming (round-12 proven) -> fp32 d_out.
//
// MFMA layouts (HW-verified): A[m=lane&15][k=quad*8+j]; B[n=lane&15][k=quad*8+j];
// C/D: row=quad*4+reg, col=lane&15.
// K frag map (natural k=d): frag(c=t>>6, nt=(t>>4)&3, ks=d>>5),
//   elem ((d&31)>>3)*128 + (t&15)*8 + (d&7).
// V frag map (sigma on key): s = 4*(t&15) + ((t>>4)&3); frag(c, dt=d>>4, s>>5),
//   elem ((s>>3)&3)*128 + (d&15)*8 + (s&7).
// P sum over hardware slots == sum over keys (permutation-invariant) because
// P and V use the same sigma.

typedef __hip_bfloat16 bf16;
typedef __attribute__((ext_vector_type(8))) short bf16x8;
typedef __attribute__((ext_vector_type(4))) float f32x4;
typedef __attribute__((ext_vector_type(4))) short short4v;

#define MFMA16(a, b, c) __builtin_amdgcn_mfma_f32_16x16x32_bf16((a), (b), (c), 0, 0, 0)

constexpr int Bn = 2, Hn = 16, Tn = 2048, Dn = 64, Cn = 1024;
constexpr size_t NE = (size_t)Bn * Tn * Cn;   // 4,194,304
constexpr size_t WE = (size_t)Cn * Cn;        // 1,048,576
constexpr float QSCALE = 0.125f * 1.44269504088896f;   // 1/8 * log2(e)

__device__ inline unsigned short bfbits(float x) {
    bf16 b = __float2bfloat16(x);
    return *(unsigned short*)&b;
}

__device__ inline bf16x8 pack8(f32x4 a, f32x4 b) {
    bf16x8 r;
#pragma unroll
    for (int i = 0; i < 4; ++i) r[i] = (short)bfbits(a[i]);
#pragma unroll
    for (int i = 0; i < 4; ++i) r[4 + i] = (short)bfbits(b[i]);
    return r;
}

__device__ inline void gl_lds16(const bf16* g, unsigned short* l) {
    __builtin_amdgcn_global_load_lds(
        (const __attribute__((address_space(1))) void*)g,
        (__attribute__((address_space(3))) void*)l, 16, 0, 0);
}

// ---------------------------------------------------------------- convert
// blocks [0,2048): x -> fragment-major. [2048,4096): W* -> fragment-major.
__global__ __launch_bounds__(256) void convert_kernel(
    const float* __restrict__ x, const float* __restrict__ wq,
    const float* __restrict__ wk, const float* __restrict__ wv,
    const float* __restrict__ wo, bf16* __restrict__ dst)
{
    int blk = blockIdx.x;
    int lane = threadIdx.x & 63;
    int lx = lane & 15, quad = lane >> 4;
    const float* src;
    size_t doff;
    if (blk < 2048) {
        int frag = blk * 4 + (threadIdx.x >> 6);   // 0..8191
        int mt = frag >> 5, kc = frag & 31;
        src = x + (size_t)(mt * 16 + lx) * Cn + kc * 32 + quad * 8;
        doff = (size_t)frag * 512 + lane * 8;
    } else {
        int w = (blk - 2048) >> 9, b = (blk - 2048) & 511;
        const float* s4[4] = {wq, wk, wv, wo};
        int frag = b * 4 + (threadIdx.x >> 6);     // 0..2047
        int nb = frag >> 5, kc = frag & 31;
        src = s4[w] + (size_t)(nb * 16 + lx) * Cn + kc * 32 + quad * 8;
        doff = NE + (size_t)w * WE + (size_t)frag * 512 + lane * 8;
    }
    f32x4 a = *(const f32x4*)(src);
    f32x4 b2 = *(const f32x4*)(src + 4);
    *(bf16x8*)(dst + doff) = pack8(a, b2);
}

// ---------------------------------------------------------------- QKV GEMM
// ZERO-LDS streaming GEMM: 4 waves (2x2), wave 64x64, K-step 32, cur/next
// prefetch, no barriers. Epilogue: Q row-major; K frag-major; V sigma-frag.
__global__ __launch_bounds__(256) void gemm_qkv_kernel(
    const bf16* __restrict__ Xf, const bf16* __restrict__ Wbase,
    bf16* __restrict__ Qo, bf16* __restrict__ Ko, bf16* __restrict__ Vo)
{
    const int bm = blockIdx.x, bn = blockIdx.y, wsel = blockIdx.z;
    const bf16* W = Wbase + (size_t)wsel * WE;
    const int tid  = threadIdx.x;
    const int wave = tid >> 6, lane = tid & 63;
    const int lx   = lane & 15, quad = lane >> 4;
    const int wm = wave >> 1, wn = wave & 1;

    const int mt0 = bm * 8 + wm * 4;
    const int nb0 = bn * 8 + wn * 4;
    const bf16* afrag = Xf + (size_t)mt0 * 32 * 512 + (size_t)lane * 8;
    const bf16* wfrag = W + (size_t)nb0 * 32 * 512 + (size_t)lane * 8;

    f32x4 acc[4][4] = {};   // [mt][nt]
    bf16x8 acur[4], bcur[4], anxt[4], bnxt[4];
#pragma unroll
    for (int i = 0; i < 4; ++i) {
        acur[i] = *(const bf16x8*)(afrag + (size_t)i * 32 * 512);
        bcur[i] = *(const bf16x8*)(wfrag + (size_t)i * 32 * 512);
    }
    for (int kc = 0; kc < 32; ++kc) {
        if (kc < 31) {
#pragma unroll
            for (int i = 0; i < 4; ++i) {
                anxt[i] = *(const bf16x8*)(afrag + ((size_t)i * 32 + kc + 1) * 512);
                bnxt[i] = *(const bf16x8*)(wfrag + ((size_t)i * 32 + kc + 1) * 512);
            }
        }
#pragma unroll
        for (int mt = 0; mt < 4; ++mt)
#pragma unroll
            for (int nt = 0; nt < 4; ++nt)
                acc[mt][nt] = MFMA16(acur[mt], bcur[nt], acc[mt][nt]);
#pragma unroll
        for (int i = 0; i < 4; ++i) { acur[i] = anxt[i]; bcur[i] = bnxt[i]; }
    }

    const int h = bn * 2 + wn;   // 64-col wave block == one head
    if (wsel <= 1) {             // fused RoPE: pair (d, d+32) = (nt, nt+2)
#pragma unroll
        for (int mt = 0; mt < 4; ++mt)
#pragma unroll
            for (int r = 0; r < 4; ++r) {
                int mg = bm * 128 + wm * 64 + mt * 16 + quad * 4 + r;
                int t  = mg & (Tn - 1);
#pragma unroll
                for (int nt = 0; nt < 2; ++nt) {
                    int d = nt * 16 + lx;   // 0..31
                    float ang = (float)t * __expf(-(float)d * 0.2878231366f);
                    float c, s;
                    __sincosf(ang, &s, &c);
                    float a0 = acc[mt][nt][r], a1 = acc[mt][nt + 2][r];
                    acc[mt][nt][r]     = a0 * c - a1 * s;
                    acc[mt][nt + 2][r] = a1 * c + a0 * s;
                }
            }
    }

#pragma unroll
    for (int mt = 0; mt < 4; ++mt) {
        int mg0 = bm * 128 + wm * 64 + mt * 16 + quad * 4;
        int b = mg0 >> 11, tlo = mg0 & (Tn - 1);
        if (wsel == 0) {        // Q: row-major [B,H,T,D], exp2-folded scale
#pragma unroll
            for (int nt = 0; nt < 4; ++nt)
#pragma unroll
                for (int r = 0; r < 4; ++r) {
                    int d = nt * 16 + lx;
                    Qo[((size_t)(b * Hn + h) * Tn + tlo + r) * Dn + d] =
                        __float2bfloat16(acc[mt][nt][r] * QSCALE);
                }
        } else if (wsel == 1) { // K: QK-B-fragment-major per head
            bf16* Kf = Ko + (size_t)(b * Hn + h) * Tn * Dn;
            int c = tlo >> 6, ntk = (tlo >> 4) & 3;
#pragma unroll
            for (int nt = 0; nt < 4; ++nt) {
                size_t base = ((size_t)(c * 4 + ntk) * 2 + (nt >> 1)) * 512
                            + (size_t)((nt & 1) * 2 + (lx >> 3)) * 128
                            + (size_t)(tlo & 15) * 8 + (lx & 7);
#pragma unroll
                for (int r = 0; r < 4; ++r)
                    Kf[base + (size_t)r * 8] = __float2bfloat16(acc[mt][nt][r]);
            }
        } else {                // V: PV-B-fragment-major, SIGMA key-permute
            bf16* Vf = Vo + (size_t)(b * Hn + h) * Tn * Dn;
            int c = tlo >> 6;
#pragma unroll
            for (int nt = 0; nt < 4; ++nt)
#pragma unroll
                for (int r = 0; r < 4; ++r) {
                    int t = tlo + r;
                    int s = 4 * (t & 15) + ((t >> 4) & 3);   // sigma slot
                    Vf[((size_t)(c * 8 + nt * 2 + (s >> 5))) * 512
                       + (size_t)((s >> 3) & 3) * 128
                       + (size_t)lx * 8 + (s & 7)] =
                        __float2bfloat16(acc[mt][nt][r]);
                }
        }
    }
}

// ---------------------------------------------------------------- out GEMM
// ZERO-LDS streaming (round-12 proven): block 128x64, wave 64x32, no barriers.
__global__ __launch_bounds__(256) void gemm_out_kernel(
    const bf16* __restrict__ Af, const bf16* __restrict__ W, float* __restrict__ Out)
{
    const int bm = blockIdx.x, bn = blockIdx.y;
    const int tid  = threadIdx.x;
    const int wave = tid >> 6, lane = tid & 63;
    const int lx   = lane & 15, quad = lane >> 4;
    const int wm = wave >> 1, wn = wave & 1;

    const int mt0 = bm * 8 + wm * 4;
    const int nb0 = bn * 4 + wn * 2;
    const bf16* afrag = Af + (size_t)mt0 * 32 * 512 + (size_t)lane * 8;
    const bf16* wfrag = W + (size_t)nb0 * 32 * 512 + (size_t)lane * 8;

    f32x4 acc[4][2] = {};
    bf16x8 acur[4], bcur[2], anxt[4], bnxt[2];
#pragma unroll
    for (int i = 0; i < 4; ++i)
        acur[i] = *(const bf16x8*)(afrag + (size_t)i * 32 * 512);
#pragma unroll
    for (int i = 0; i < 2; ++i)
        bcur[i] = *(const bf16x8*)(wfrag + (size_t)i * 32 * 512);
    for (int kc = 0; kc < 32; ++kc) {
        if (kc < 31) {
#pragma unroll
            for (int i = 0; i < 4; ++i)
                anxt[i] = *(const bf16x8*)(afrag + ((size_t)i * 32 + kc + 1) * 512);
#pragma unroll
            for (int i = 0; i < 2; ++i)
                bnxt[i] = *(const bf16x8*)(wfrag + ((size_t)i * 32 + kc + 1) * 512);
        }
#pragma unroll
        for (int mt = 0; mt < 4; ++mt)
#pragma unroll
            for (int nt = 0; nt < 2; ++nt)
                acc[mt][nt] = MFMA16(acur[mt], bcur[nt], acc[mt][nt]);
#pragma unroll
        for (int i = 0; i < 4; ++i) acur[i] = anxt[i];
#pragma unroll
        for (int i = 0; i < 2; ++i) bcur[i] = bnxt[i];
    }
#pragma unroll
    for (int mt = 0; mt < 4; ++mt)
#pragma unroll
        for (int nt = 0; nt < 2; ++nt)
#pragma unroll
            for (int r = 0; r < 4; ++r) {
                int mg = bm * 128 + wm * 64 + mt * 16 + quad * 4 + r;
                int ng = bn * 64 + wn * 32 + nt * 16 + lx;
                Out[(size_t)mg * Cn + ng] = acc[mt][nt][r];
            }
}

// ---------------------------------------------------------------- Attention
// 1024 blocks: f -> bh = (f&7)*4 + ((f>>3)&3), qb = 31 - (f>>5).
// One 64-row q-tile per block, 4 waves x 16 rows. K/V frag-major chunks
// flat-staged in LDS once per block (8 KB each); fragment reads are
// ds_read_b128 at immediate offsets. P: sigma-packed ds_write_b64 x4.
__global__ __launch_bounds__(256) void attn_kernel(
    const bf16* __restrict__ Q, const bf16* __restrict__ K,
    const bf16* __restrict__ Vt, bf16* __restrict__ O)
{
    __shared__ unsigned short Ks[4096];
    __shared__ unsigned short Vs[4096];
    __shared__ unsigned short Pl[4][16 * 72];
    const int f  = blockIdx.x;
    const int bh = (f & 7) * 4 + ((f >> 3) & 3);
    const int qb = 31 - (f >> 5);
    const int tid  = threadIdx.x;
    const int wave = tid >> 6, lane = tid & 63;
    const int lx   = lane & 15, quad = lane >> 4;

    const bf16* Qh = Q  + (size_t)bh * Tn * Dn;
    const bf16* Kh = K  + (size_t)bh * Tn * Dn;   // frag-major, 4096/chunk
    const bf16* Vh = Vt + (size_t)bh * Tn * Dn;   // sigma-frag-major
    unsigned short* pw = &Pl[wave][0];

    const int qrowA = qb * 64 + wave * 16 + lx;   // A-frag m index
    bf16x8 aq0 = *(const bf16x8*)(Qh + (size_t)qrowA * Dn + quad * 8);
    bf16x8 aq1 = *(const bf16x8*)(Qh + (size_t)qrowA * Dn + 32 + quad * 8);

    bf16x8 ones;
#pragma unroll
    for (int i = 0; i < 8; ++i) ones[i] = (short)0x3F80;

    f32x4 acc_o[4] = {};
    f32x4 acc_l = {};
    const int row_local = wave * 16 + quad * 4;

    for (int c = 0; c <= qb; ++c) {
        __syncthreads();
        // flat-stage the 8KB K and V chunks (shared by all 4 waves).
        // global addr is PER-LANE (+ lane*8); LDS base is wave-uniform
        // (HW adds lane*16B) — this was the round-14 bug.
#pragma unroll
        for (int j = 0; j < 2; ++j) {
            int base = (j * 256 + wave * 64) * 8;     // wave-uniform, shorts
            gl_lds16(Kh + (size_t)c * 4096 + base + lane * 8, Ks + base);
            gl_lds16(Vh + (size_t)c * 4096 + base + lane * 8, Vs + base);
        }
        __syncthreads();
        // ---- S = Q K^T (exp2 scale pre-folded into Q)
        f32x4 accs[4] = {};
#pragma unroll
        for (int nt = 0; nt < 4; ++nt) {
            bf16x8 k0 = *(const bf16x8*)&Ks[(nt * 2) * 512 + lane * 8];
            bf16x8 k1 = *(const bf16x8*)&Ks[(nt * 2 + 1) * 512 + lane * 8];
            accs[nt] = MFMA16(aq0, k0, accs[nt]);
            accs[nt] = MFMA16(aq1, k1, accs[nt]);
        }
        // ---- p = exp2(s): sigma-packed write, slot = 4*lx + nt -> b64
        if (c < qb) {
#pragma unroll
            for (int r = 0; r < 4; ++r) {
                short4v pk;
#pragma unroll
                for (int nt = 0; nt < 4; ++nt)
                    pk[nt] = (short)bfbits(exp2f(accs[nt][r]));
                *(short4v*)&pw[(quad * 4 + r) * 72 + lx * 4] = pk;
            }
        } else {   // diagonal chunk: causal mask
#pragma unroll
            for (int r = 0; r < 4; ++r) {
                short4v pk;
#pragma unroll
                for (int nt = 0; nt < 4; ++nt) {
                    int keyl = nt * 16 + lx;
                    float p = (keyl > row_local + r) ? 0.0f : exp2f(accs[nt][r]);
                    pk[nt] = (short)bfbits(p);
                }
                *(short4v*)&pw[(quad * 4 + r) * 72 + lx * 4] = pk;
            }
        }
        asm volatile("s_waitcnt lgkmcnt(0)" ::: "memory");
        bf16x8 ap0 = *(const bf16x8*)&pw[lx * 72 + quad * 8];
        bf16x8 ap1 = *(const bf16x8*)&pw[lx * 72 + 32 + quad * 8];
        // ---- l += P . 1 (permutation-invariant)
        acc_l = MFMA16(ap0, ones, acc_l);
        acc_l = MFMA16(ap1, ones, acc_l);
        // ---- O += P V (V sigma-slotted to match P)
#pragma unroll
        for (int dt = 0; dt < 4; ++dt) {
            bf16x8 v0 = *(const bf16x8*)&Vs[(dt * 2) * 512 + lane * 8];
            bf16x8 v1 = *(const bf16x8*)&Vs[(dt * 2 + 1) * 512 + lane * 8];
            acc_o[dt] = MFMA16(ap0, v0, acc_o[dt]);
            acc_o[dt] = MFMA16(ap1, v1, acc_o[dt]);
        }
    }

    // epilogue: fragment-major O write (for streaming out-GEMM)
    const int b = bh >> 4, h = bh & 15;
    const int mtile = b * 128 + qb * 4 + wave;
#pragma unroll
    for (int dt = 0; dt < 4; ++dt) {
        int ch = h * 64 + dt * 16 + lx;            // channel
        size_t base = ((size_t)mtile * 32 + (ch >> 5)) * 512
                    + (size_t)(((ch >> 3) & 3) * 16) * 8 + (ch & 7);
#pragma unroll
        for (int r = 0; r < 4; ++r) {
            float o = acc_o[dt][r] / acc_l[r];
            O[base + (size_t)(quad * 4 + r) * 8] = __float2bfloat16(o);
        }
    }
}

// ---------------------------------------------------------------- launch
extern "C" void kernel_launch(void* const* d_in, const int* in_sizes, int n_in,
                              void* d_out, int out_size, void* d_ws, size_t ws_size,
                              hipStream_t stream)
{
    const float* x  = (const float*)d_in[0];
    const float* Wq = (const float*)d_in[1];
    const float* Wk = (const float*)d_in[2];
    const float* Wv = (const float*)d_in[3];
    const float* Wo = (const float*)d_in[4];
    float* out = (float*)d_out;

    bf16* ws = (bf16*)d_ws;
    bf16* Xf = ws;                    // x fragment-major (aliased by Ab after QKV)
    bf16* Wb = ws + NE;               // Wq,Wk,Wv,Wo bf16 SHUFFLED, contiguous
    bf16* Qb = ws + NE + 4 * WE;      // [B,H,T,D] (pre-scaled by QSCALE)
    bf16* Kb = Qb + NE;               // QK-B-fragment-major per head
    bf16* Vb = Kb + NE;               // PV-B-fragment-major (sigma) per head
    bf16* Ab = Xf;                    // attention out FRAGMENT-MAJOR, reuses Xf

    convert_kernel<<<4096, 256, 0, stream>>>(x, Wq, Wk, Wv, Wo, ws);
    gemm_qkv_kernel<<<dim3(32, 8, 3), 256, 0, stream>>>(Xf, Wb, Qb, Kb, Vb);
    attn_kernel<<<1024, 256, 0, stream>>>(Qb, Kb, Vb, Ab);
    gemm_out_kernel<<<dim3(32, 16), 256, 0, stream>>>(Ab, Wb + 3 * WE, out);
}

// Round 16
// 175.016 us; speedup vs baseline: 1.0227x; 1.0101x over previous
//
#include <hip/hip_runtime.h>
#include <hip/hip_bf16.h>

// MultiHeadAttention fused pipeline. FP32 in/out, bf16 MFMA compute, fp32 accum.
// B=2 T=2048 C=1024 H=16 D=64.
// Stage 0: convert x,W* -> bf16 fragment-major (wave frag load = 1KB burst).
// Stage 1: QKV GEMM zero-LDS streaming; RoPE + exp2 scale fused.
//          Q row-major; K QK-B-frag-major (scalar stores, stride-8);
//          V PV-B-frag-major NATURAL k-order -> 8B short4v stores (r13-proven).
// Stage 2: attention: frag-major K/V chunks flat-staged in LDS once per block
//          (global_load_lds per-lane addr), immediate-offset ds_read_b128
//          fragment reads (no swizzle VALU); p = exp2(s) no-max softmax;
//          P written scalar b16 at slot=key (natural, matches V); l via
//          ones-MFMA; per-wave P. O written fragment-major.
// Stage 3: out GEMM zero-LDS streaming -> fp32 d_out.
//
// MFMA layouts (HW-verified): A[m=lane&15][k=quad*8+j]; B[n=lane&15][k=quad*8+j];
// C/D: row=quad*4+reg, col=lane&15.
// K frag map (k=d): frag(c=t>>6, nt=(t>>4)&3, ks=d>>5),
//   elem ((d&31)>>3)*128 + (t&15)*8 + (d&7).
// V frag map (k=t natural): frag(c=t>>6, dt=d>>4, ks=(t>>5)&1),
//   elem ((t&31)>>3)*128 + (d&15)*8 + (t&7)  -> r-contiguous: 8B stores.

typedef __hip_bfloat16 bf16;
typedef __attribute__((ext_vector_type(8))) short bf16x8;
typedef __attribute__((ext_vector_type(4))) float f32x4;
typedef __attribute__((ext_vector_type(4))) short short4v;

#define MFMA16(a, b, c) __builtin_amdgcn_mfma_f32_16x16x32_bf16((a), (b), (c), 0, 0, 0)

constexpr int Bn = 2, Hn = 16, Tn = 2048, Dn = 64, Cn = 1024;
constexpr size_t NE = (size_t)Bn * Tn * Cn;   // 4,194,304
constexpr size_t WE = (size_t)Cn * Cn;        // 1,048,576
constexpr float QSCALE = 0.125f * 1.44269504088896f;   // 1/8 * log2(e)

__device__ inline unsigned short bfbits(float x) {
    bf16 b = __float2bfloat16(x);
    return *(unsigned short*)&b;
}

__device__ inline bf16x8 pack8(f32x4 a, f32x4 b) {
    bf16x8 r;
#pragma unroll
    for (int i = 0; i < 4; ++i) r[i] = (short)bfbits(a[i]);
#pragma unroll
    for (int i = 0; i < 4; ++i) r[4 + i] = (short)bfbits(b[i]);
    return r;
}

__device__ inline void gl_lds16(const bf16* g, unsigned short* l) {
    __builtin_amdgcn_global_load_lds(
        (const __attribute__((address_space(1))) void*)g,
        (__attribute__((address_space(3))) void*)l, 16, 0, 0);
}

// ---------------------------------------------------------------- convert
// blocks [0,2048): x -> fragment-major. [2048,4096): W* -> fragment-major.
__global__ __launch_bounds__(256) void convert_kernel(
    const float* __restrict__ x, const float* __restrict__ wq,
    const float* __restrict__ wk, const float* __restrict__ wv,
    const float* __restrict__ wo, bf16* __restrict__ dst)
{
    int blk = blockIdx.x;
    int lane = threadIdx.x & 63;
    int lx = lane & 15, quad = lane >> 4;
    const float* src;
    size_t doff;
    if (blk < 2048) {
        int frag = blk * 4 + (threadIdx.x >> 6);   // 0..8191
        int mt = frag >> 5, kc = frag & 31;
        src = x + (size_t)(mt * 16 + lx) * Cn + kc * 32 + quad * 8;
        doff = (size_t)frag * 512 + lane * 8;
    } else {
        int w = (blk - 2048) >> 9, b = (blk - 2048) & 511;
        const float* s4[4] = {wq, wk, wv, wo};
        int frag = b * 4 + (threadIdx.x >> 6);     // 0..2047
        int nb = frag >> 5, kc = frag & 31;
        src = s4[w] + (size_t)(nb * 16 + lx) * Cn + kc * 32 + quad * 8;
        doff = NE + (size_t)w * WE + (size_t)frag * 512 + lane * 8;
    }
    f32x4 a = *(const f32x4*)(src);
    f32x4 b2 = *(const f32x4*)(src + 4);
    *(bf16x8*)(dst + doff) = pack8(a, b2);
}

// ---------------------------------------------------------------- QKV GEMM
// ZERO-LDS streaming GEMM: 4 waves (2x2), wave 64x64, K-step 32, cur/next
// prefetch, no barriers. Epilogue: Q row-major; K frag-major; V natural-frag
// (8B short4v stores).
__global__ __launch_bounds__(256) void gemm_qkv_kernel(
    const bf16* __restrict__ Xf, const bf16* __restrict__ Wbase,
    bf16* __restrict__ Qo, bf16* __restrict__ Ko, bf16* __restrict__ Vo)
{
    const int bm = blockIdx.x, bn = blockIdx.y, wsel = blockIdx.z;
    const bf16* W = Wbase + (size_t)wsel * WE;
    const int tid  = threadIdx.x;
    const int wave = tid >> 6, lane = tid & 63;
    const int lx   = lane & 15, quad = lane >> 4;
    const int wm = wave >> 1, wn = wave & 1;

    const int mt0 = bm * 8 + wm * 4;
    const int nb0 = bn * 8 + wn * 4;
    const bf16* afrag = Xf + (size_t)mt0 * 32 * 512 + (size_t)lane * 8;
    const bf16* wfrag = W + (size_t)nb0 * 32 * 512 + (size_t)lane * 8;

    f32x4 acc[4][4] = {};   // [mt][nt]
    bf16x8 acur[4], bcur[4], anxt[4], bnxt[4];
#pragma unroll
    for (int i = 0; i < 4; ++i) {
        acur[i] = *(const bf16x8*)(afrag + (size_t)i * 32 * 512);
        bcur[i] = *(const bf16x8*)(wfrag + (size_t)i * 32 * 512);
    }
    for (int kc = 0; kc < 32; ++kc) {
        if (kc < 31) {
#pragma unroll
            for (int i = 0; i < 4; ++i) {
                anxt[i] = *(const bf16x8*)(afrag + ((size_t)i * 32 + kc + 1) * 512);
                bnxt[i] = *(const bf16x8*)(wfrag + ((size_t)i * 32 + kc + 1) * 512);
            }
        }
#pragma unroll
        for (int mt = 0; mt < 4; ++mt)
#pragma unroll
            for (int nt = 0; nt < 4; ++nt)
                acc[mt][nt] = MFMA16(acur[mt], bcur[nt], acc[mt][nt]);
#pragma unroll
        for (int i = 0; i < 4; ++i) { acur[i] = anxt[i]; bcur[i] = bnxt[i]; }
    }

    const int h = bn * 2 + wn;   // 64-col wave block == one head
    if (wsel <= 1) {             // fused RoPE: pair (d, d+32) = (nt, nt+2)
#pragma unroll
        for (int mt = 0; mt < 4; ++mt)
#pragma unroll
            for (int r = 0; r < 4; ++r) {
                int mg = bm * 128 + wm * 64 + mt * 16 + quad * 4 + r;
                int t  = mg & (Tn - 1);
#pragma unroll
                for (int nt = 0; nt < 2; ++nt) {
                    int d = nt * 16 + lx;   // 0..31
                    float ang = (float)t * __expf(-(float)d * 0.2878231366f);
                    float c, s;
                    __sincosf(ang, &s, &c);
                    float a0 = acc[mt][nt][r], a1 = acc[mt][nt + 2][r];
                    acc[mt][nt][r]     = a0 * c - a1 * s;
                    acc[mt][nt + 2][r] = a1 * c + a0 * s;
                }
            }
    }

#pragma unroll
    for (int mt = 0; mt < 4; ++mt) {
        int mg0 = bm * 128 + wm * 64 + mt * 16 + quad * 4;
        int b = mg0 >> 11, tlo = mg0 & (Tn - 1);
        if (wsel == 0) {        // Q: row-major [B,H,T,D], exp2-folded scale
#pragma unroll
            for (int nt = 0; nt < 4; ++nt)
#pragma unroll
                for (int r = 0; r < 4; ++r) {
                    int d = nt * 16 + lx;
                    Qo[((size_t)(b * Hn + h) * Tn + tlo + r) * Dn + d] =
                        __float2bfloat16(acc[mt][nt][r] * QSCALE);
                }
        } else if (wsel == 1) { // K: QK-B-fragment-major per head
            bf16* Kf = Ko + (size_t)(b * Hn + h) * Tn * Dn;
            int c = tlo >> 6, ntk = (tlo >> 4) & 3;
#pragma unroll
            for (int nt = 0; nt < 4; ++nt) {
                size_t base = ((size_t)(c * 4 + ntk) * 2 + (nt >> 1)) * 512
                            + (size_t)((nt & 1) * 2 + (lx >> 3)) * 128
                            + (size_t)(tlo & 15) * 8 + (lx & 7);
#pragma unroll
                for (int r = 0; r < 4; ++r)
                    Kf[base + (size_t)r * 8] = __float2bfloat16(acc[mt][nt][r]);
            }
        } else {                // V: natural-k frag-major, 8B stores (r13)
            bf16* Vf = Vo + (size_t)(b * Hn + h) * Tn * Dn;
            int c = tlo >> 6, ksv = (tlo >> 5) & 1;
            int qv = (tlo >> 3) & 3, pos0 = tlo & 7;
#pragma unroll
            for (int nt = 0; nt < 4; ++nt) {
                short4v pk;
#pragma unroll
                for (int r = 0; r < 4; ++r) pk[r] = (short)bfbits(acc[mt][nt][r]);
                *(short4v*)&Vf[((size_t)(c * 8 + nt * 2 + ksv)) * 512
                               + (size_t)qv * 128 + (size_t)lx * 8 + pos0] = pk;
            }
        }
    }
}

// ---------------------------------------------------------------- out GEMM
// ZERO-LDS streaming: block 128x64, wave 64x32, no barriers.
__global__ __launch_bounds__(256) void gemm_out_kernel(
    const bf16* __restrict__ Af, const bf16* __restrict__ W, float* __restrict__ Out)
{
    const int bm = blockIdx.x, bn = blockIdx.y;
    const int tid  = threadIdx.x;
    const int wave = tid >> 6, lane = tid & 63;
    const int lx   = lane & 15, quad = lane >> 4;
    const int wm = wave >> 1, wn = wave & 1;

    const int mt0 = bm * 8 + wm * 4;
    const int nb0 = bn * 4 + wn * 2;
    const bf16* afrag = Af + (size_t)mt0 * 32 * 512 + (size_t)lane * 8;
    const bf16* wfrag = W + (size_t)nb0 * 32 * 512 + (size_t)lane * 8;

    f32x4 acc[4][2] = {};
    bf16x8 acur[4], bcur[2], anxt[4], bnxt[2];
#pragma unroll
    for (int i = 0; i < 4; ++i)
        acur[i] = *(const bf16x8*)(afrag + (size_t)i * 32 * 512);
#pragma unroll
    for (int i = 0; i < 2; ++i)
        bcur[i] = *(const bf16x8*)(wfrag + (size_t)i * 32 * 512);
    for (int kc = 0; kc < 32; ++kc) {
        if (kc < 31) {
#pragma unroll
            for (int i = 0; i < 4; ++i)
                anxt[i] = *(const bf16x8*)(afrag + ((size_t)i * 32 + kc + 1) * 512);
#pragma unroll
            for (int i = 0; i < 2; ++i)
                bnxt[i] = *(const bf16x8*)(wfrag + ((size_t)i * 32 + kc + 1) * 512);
        }
#pragma unroll
        for (int mt = 0; mt < 4; ++mt)
#pragma unroll
            for (int nt = 0; nt < 2; ++nt)
                acc[mt][nt] = MFMA16(acur[mt], bcur[nt], acc[mt][nt]);
#pragma unroll
        for (int i = 0; i < 4; ++i) acur[i] = anxt[i];
#pragma unroll
        for (int i = 0; i < 2; ++i) bcur[i] = bnxt[i];
    }
#pragma unroll
    for (int mt = 0; mt < 4; ++mt)
#pragma unroll
        for (int nt = 0; nt < 2; ++nt)
#pragma unroll
            for (int r = 0; r < 4; ++r) {
                int mg = bm * 128 + wm * 64 + mt * 16 + quad * 4 + r;
                int ng = bn * 64 + wn * 32 + nt * 16 + lx;
                Out[(size_t)mg * Cn + ng] = acc[mt][nt][r];
            }
}

// ---------------------------------------------------------------- Attention
// 1024 blocks: f -> bh = (f&7)*4 + ((f>>3)&3), qb = 31 - (f>>5).
// One 64-row q-tile per block, 4 waves x 16 rows. K/V frag-major chunks
// flat-staged in LDS once per block (8 KB each, per-lane global addr);
// fragment reads are ds_read_b128 at immediate offsets. P scalar b16 at
// slot=key (natural order, matches V's natural-k layout).
__global__ __launch_bounds__(256) void attn_kernel(
    const bf16* __restrict__ Q, const bf16* __restrict__ K,
    const bf16* __restrict__ Vt, bf16* __restrict__ O)
{
    __shared__ unsigned short Ks[4096];
    __shared__ unsigned short Vs[4096];
    __shared__ unsigned short Pl[4][16 * 72];
    const int f  = blockIdx.x;
    const int bh = (f & 7) * 4 + ((f >> 3) & 3);
    const int qb = 31 - (f >> 5);
    const int tid  = threadIdx.x;
    const int wave = tid >> 6, lane = tid & 63;
    const int lx   = lane & 15, quad = lane >> 4;

    const bf16* Qh = Q  + (size_t)bh * Tn * Dn;
    const bf16* Kh = K  + (size_t)bh * Tn * Dn;   // frag-major, 4096/chunk
    const bf16* Vh = Vt + (size_t)bh * Tn * Dn;   // natural-k frag-major
    unsigned short* pw = &Pl[wave][0];

    const int qrowA = qb * 64 + wave * 16 + lx;   // A-frag m index
    bf16x8 aq0 = *(const bf16x8*)(Qh + (size_t)qrowA * Dn + quad * 8);
    bf16x8 aq1 = *(const bf16x8*)(Qh + (size_t)qrowA * Dn + 32 + quad * 8);

    bf16x8 ones;
#pragma unroll
    for (int i = 0; i < 8; ++i) ones[i] = (short)0x3F80;

    f32x4 acc_o[4] = {};
    f32x4 acc_l = {};
    const int row_local = wave * 16 + quad * 4;

    for (int c = 0; c <= qb; ++c) {
        __syncthreads();
        // flat-stage the 8KB K and V chunks (per-lane global addr,
        // wave-uniform LDS base — HW adds lane*16B on the LDS side)
#pragma unroll
        for (int j = 0; j < 2; ++j) {
            int base = (j * 256 + wave * 64) * 8;     // wave-uniform, shorts
            gl_lds16(Kh + (size_t)c * 4096 + base + lane * 8, Ks + base);
            gl_lds16(Vh + (size_t)c * 4096 + base + lane * 8, Vs + base);
        }
        __syncthreads();
        // ---- S = Q K^T (exp2 scale pre-folded into Q)
        f32x4 accs[4] = {};
#pragma unroll
        for (int nt = 0; nt < 4; ++nt) {
            bf16x8 k0 = *(const bf16x8*)&Ks[(nt * 2) * 512 + lane * 8];
            bf16x8 k1 = *(const bf16x8*)&Ks[(nt * 2 + 1) * 512 + lane * 8];
            accs[nt] = MFMA16(aq0, k0, accs[nt]);
            accs[nt] = MFMA16(aq1, k1, accs[nt]);
        }
        // ---- p = exp2(s) -> per-wave P buffer, slot = key (natural)
        if (c < qb) {
#pragma unroll
            for (int nt = 0; nt < 4; ++nt)
#pragma unroll
                for (int r = 0; r < 4; ++r)
                    pw[(quad * 4 + r) * 72 + nt * 16 + lx] = bfbits(exp2f(accs[nt][r]));
        } else {   // diagonal chunk: causal mask
#pragma unroll
            for (int nt = 0; nt < 4; ++nt) {
                int keyl = nt * 16 + lx;
#pragma unroll
                for (int r = 0; r < 4; ++r) {
                    float p = (keyl > row_local + r) ? 0.0f : exp2f(accs[nt][r]);
                    pw[(quad * 4 + r) * 72 + nt * 16 + lx] = bfbits(p);
                }
            }
        }
        asm volatile("s_waitcnt lgkmcnt(0)" ::: "memory");
        bf16x8 ap0 = *(const bf16x8*)&pw[lx * 72 + quad * 8];
        bf16x8 ap1 = *(const bf16x8*)&pw[lx * 72 + 32 + quad * 8];
        // ---- l += P . 1
        acc_l = MFMA16(ap0, ones, acc_l);
        acc_l = MFMA16(ap1, ones, acc_l);
        // ---- O += P V (natural k order on both sides)
#pragma unroll
        for (int dt = 0; dt < 4; ++dt) {
            bf16x8 v0 = *(const bf16x8*)&Vs[(dt * 2) * 512 + lane * 8];
            bf16x8 v1 = *(const bf16x8*)&Vs[(dt * 2 + 1) * 512 + lane * 8];
            acc_o[dt] = MFMA16(ap0, v0, acc_o[dt]);
            acc_o[dt] = MFMA16(ap1, v1, acc_o[dt]);
        }
    }

    // epilogue: fragment-major O write (for streaming out-GEMM)
    const int b = bh >> 4, h = bh & 15;
    const int mtile = b * 128 + qb * 4 + wave;
#pragma unroll
    for (int dt = 0; dt < 4; ++dt) {
        int ch = h * 64 + dt * 16 + lx;            // channel
        size_t base = ((size_t)mtile * 32 + (ch >> 5)) * 512
                    + (size_t)(((ch >> 3) & 3) * 16) * 8 + (ch & 7);
#pragma unroll
        for (int r = 0; r < 4; ++r) {
            float o = acc_o[dt][r] / acc_l[r];
            O[base + (size_t)(quad * 4 + r) * 8] = __float2bfloat16(o);
        }
    }
}

// ---------------------------------------------------------------- launch
extern "C" void kernel_launch(void* const* d_in, const int* in_sizes, int n_in,
                              void* d_out, int out_size, void* d_ws, size_t ws_size,
                              hipStream_t stream)
{
    const float* x  = (const float*)d_in[0];
    const float* Wq = (const float*)d_in[1];
    const float* Wk = (const float*)d_in[2];
    const float* Wv = (const float*)d_in[3];
    const float* Wo = (const float*)d_in[4];
    float* out = (float*)d_out;

    bf16* ws = (bf16*)d_ws;
    bf16* Xf = ws;                    // x fragment-major (aliased by Ab after QKV)
    bf16* Wb = ws + NE;               // Wq,Wk,Wv,Wo bf16 SHUFFLED, contiguous
    bf16* Qb = ws + NE + 4 * WE;      // [B,H,T,D] (pre-scaled by QSCALE)
    bf16* Kb = Qb + NE;               // QK-B-fragment-major per head
    bf16* Vb = Kb + NE;               // PV-B-fragment-major (natural k) per head
    bf16* Ab = Xf;                    // attention out FRAGMENT-MAJOR, reuses Xf

    convert_kernel<<<4096, 256, 0, stream>>>(x, Wq, Wk, Wv, Wo, ws);
    gemm_qkv_kernel<<<dim3(32, 8, 3), 256, 0, stream>>>(Xf, Wb, Qb, Kb, Vb);
    attn_kernel<<<1024, 256, 0, stream>>>(Qb, Kb, Vb, Ab);
    gemm_out_kernel<<<dim3(32, 16), 256, 0, stream>>>(Ab, Wb + 3 * WE, out);
}